// Round 18
// baseline (285.791 us; speedup 1.0000x reference)
//
#include <hip/hip_runtime.h>
#include <hip/hip_bf16.h>

#define N_NODES 100000
#define N_EDGES 600000
#define HIDDEN 128
#define N_LAYERS 4
#define MPAD 100096   // N_NODES rounded up to 128 (and to 64)
#define CPAD 16       // counter padding: one counter per 64B line

#define TAP0_BLOCKS ((N_NODES * 16) / 256)                       // 6250
#define CNT_BLOCKS ((N_EDGES + 255) / 256)                       // 2344
#define PREPW_BLOCKS ((N_LAYERS * HIDDEN * HIDDEN + 255) / 256)  // 256
#define GEMM_BLOCKS (MPAD / 64)                                  // 1564

typedef short bf16x8 __attribute__((ext_vector_type(8)));
typedef float f32x4 __attribute__((ext_vector_type(4)));
typedef float f32x8 __attribute__((ext_vector_type(8)));

__device__ inline ushort f2bf(float f) {
    __hip_bfloat16 h = __float2bfloat16(f);
    return *reinterpret_cast<ushort*>(&h);
}

__device__ inline float bfhi(uint u) { return __uint_as_float(u << 16); }
__device__ inline float bflo(uint u) { return __uint_as_float(u & 0xffff0000u); }

// Gather body: 16 lanes/node, uint4/lane, exact-width 6/4/2/1 ladder.
// 6-wide head: deg-6 mode completes in ONE latency round (R14's 4/2/1 took
// two). Single shared body (R9 lesson), no padded requests (R7 lesson),
// FMA order e0->e5 sequential = identical arithmetic to R14.
#define FMA8(U, P) { float wk = __int_as_float(P.y); \
    a[0] += bfhi(U.x) * wk; a[1] += bflo(U.x) * wk; \
    a[2] += bfhi(U.y) * wk; a[3] += bflo(U.y) * wk; \
    a[4] += bfhi(U.z) * wk; a[5] += bflo(U.z) * wk; \
    a[6] += bfhi(U.w) * wk; a[7] += bflo(U.w) * wk; }

__device__ __forceinline__ void gather_agg(const char* __restrict__ hrow,
                                           const int2* __restrict__ epack,
                                           int j0, int j1, int cb, float* a) {
    int j = j0;
    for (; j + 6 <= j1; j += 6) {
        int2 p0 = epack[j], p1 = epack[j + 1], p2 = epack[j + 2];
        int2 p3 = epack[j + 3], p4 = epack[j + 4], p5 = epack[j + 5];
        uint4 u0 = *(const uint4*)(hrow + (size_t)p0.x * 256 + cb);
        uint4 u1 = *(const uint4*)(hrow + (size_t)p1.x * 256 + cb);
        uint4 u2 = *(const uint4*)(hrow + (size_t)p2.x * 256 + cb);
        uint4 u3 = *(const uint4*)(hrow + (size_t)p3.x * 256 + cb);
        uint4 u4 = *(const uint4*)(hrow + (size_t)p4.x * 256 + cb);
        uint4 u5 = *(const uint4*)(hrow + (size_t)p5.x * 256 + cb);
        FMA8(u0, p0); FMA8(u1, p1); FMA8(u2, p2);
        FMA8(u3, p3); FMA8(u4, p4); FMA8(u5, p5);
    }
    if (j + 4 <= j1) {
        int2 p0 = epack[j], p1 = epack[j + 1], p2 = epack[j + 2], p3 = epack[j + 3];
        uint4 u0 = *(const uint4*)(hrow + (size_t)p0.x * 256 + cb);
        uint4 u1 = *(const uint4*)(hrow + (size_t)p1.x * 256 + cb);
        uint4 u2 = *(const uint4*)(hrow + (size_t)p2.x * 256 + cb);
        uint4 u3 = *(const uint4*)(hrow + (size_t)p3.x * 256 + cb);
        FMA8(u0, p0); FMA8(u1, p1); FMA8(u2, p2); FMA8(u3, p3);
        j += 4;
    }
    if (j + 2 <= j1) {
        int2 p0 = epack[j], p1 = epack[j + 1];
        uint4 u0 = *(const uint4*)(hrow + (size_t)p0.x * 256 + cb);
        uint4 u1 = *(const uint4*)(hrow + (size_t)p1.x * 256 + cb);
        FMA8(u0, p0); FMA8(u1, p1);
        j += 2;
    }
    if (j < j1) {
        int2 p0 = epack[j];
        uint4 u0 = *(const uint4*)(hrow + (size_t)p0.x * 256 + cb);
        FMA8(u0, p0);
    }
}

// ===========================================================================
// Prologue (fused independent prep): tap0+cast x0 | count_dst(+eslot) | prep_w
// ===========================================================================
__global__ void prologue(const float* __restrict__ x, const float* __restrict__ We,
                         const float* __restrict__ be, const float* __restrict__ temp,
                         float* __restrict__ energy, uint* __restrict__ xb,
                         const int* __restrict__ dst, int* __restrict__ cnt,
                         int* __restrict__ eslot,
                         const float* __restrict__ Ws, ushort* __restrict__ whi,
                         ushort* __restrict__ wlo) {
    int b = blockIdx.x;
    if (b < TAP0_BLOCKS) {
        int gtid = b * 256 + threadIdx.x;
        int n = gtid >> 4, l16 = gtid & 15;
        f32x8 v = *(const f32x8*)(x + (size_t)n * HIDDEN + l16 * 8);
        uint4 packed;
        packed.x = (uint)f2bf(v[0]) | ((uint)f2bf(v[1]) << 16);
        packed.y = (uint)f2bf(v[2]) | ((uint)f2bf(v[3]) << 16);
        packed.z = (uint)f2bf(v[4]) | ((uint)f2bf(v[5]) << 16);
        packed.w = (uint)f2bf(v[6]) | ((uint)f2bf(v[7]) << 16);
        ((uint4*)(xb + (size_t)n * 64))[l16] = packed;
        f32x8 we = *(const f32x8*)(We + l16 * 8);
        float dot = v[0] * we[0] + v[1] * we[1] + v[2] * we[2] + v[3] * we[3]
                  + v[4] * we[4] + v[5] * we[5] + v[6] * we[6] + v[7] * we[7];
        #pragma unroll
        for (int off = 8; off > 0; off >>= 1) dot += __shfl_xor(dot, off);
        if (l16 == 0) energy[n] = (dot + be[0]) * temp[0];
    } else if (b < TAP0_BLOCKS + CNT_BLOCKS) {
        int e = (b - TAP0_BLOCKS) * 256 + threadIdx.x;
        if (e < N_EDGES)
            eslot[e] = atomicAdd(&cnt[(size_t)dst[e] * CPAD], 1);
    } else {
        int idx = (b - TAP0_BLOCKS - CNT_BLOCKS) * 256 + threadIdx.x;
        if (idx < N_LAYERS * HIDDEN * HIDDEN) {
            int l = idx >> 14;
            int r = idx & 16383;
            int c = r >> 7, k = r & 127;
            float v = Ws[(l << 14) + k * HIDDEN + c];
            ushort hi = f2bf(v);
            float hif = __uint_as_float(((uint)hi) << 16);
            whi[idx] = hi;
            wlo[idx] = f2bf(v - hif);
        }
    }
}

// ===========================================================================
// Exclusive scan over padded cnt -> rowptr (scan1 + merged scan23)
// ===========================================================================
__global__ void scan1(const int* __restrict__ cnt, int* __restrict__ excl,
                      int* __restrict__ bsums, int n) {
    __shared__ int lds[8];
    int t = threadIdx.x;
    int base = blockIdx.x * 1024 + t * 4;
    int v0 = (base + 0 < n) ? cnt[(size_t)(base + 0) * CPAD] : 0;
    int v1 = (base + 1 < n) ? cnt[(size_t)(base + 1) * CPAD] : 0;
    int v2 = (base + 2 < n) ? cnt[(size_t)(base + 2) * CPAD] : 0;
    int v3 = (base + 3 < n) ? cnt[(size_t)(base + 3) * CPAD] : 0;
    int tsum = v0 + v1 + v2 + v3;
    int lane = t & 63, wv = t >> 6;
    int s = tsum;
    #pragma unroll
    for (int off = 1; off < 64; off <<= 1) {
        int u = __shfl_up(s, off);
        if (lane >= off) s += u;
    }
    if (lane == 63) lds[wv] = s;
    __syncthreads();
    if (t == 0) {
        int a = 0;
        #pragma unroll
        for (int i = 0; i < 4; ++i) { int bb = lds[i]; lds[i] = a; a += bb; }
        lds[4] = a;
    }
    __syncthreads();
    int excl_t = (s - tsum) + lds[wv];
    if (base + 0 < n) excl[base + 0] = excl_t;
    if (base + 1 < n) excl[base + 1] = excl_t + v0;
    if (base + 2 < n) excl[base + 2] = excl_t + v0 + v1;
    if (base + 3 < n) excl[base + 3] = excl_t + v0 + v1 + v2;
    if (t == 0) bsums[blockIdx.x] = lds[4];
}

__global__ void scan23(const int* __restrict__ excl, const int* __restrict__ bsums,
                       int* __restrict__ rowptr, int n, int nb) {
    __shared__ int bp[128];
    int t = threadIdx.x;
    if (t < nb) bp[t] = bsums[t];
    __syncthreads();
    if (t == 0) {
        int a = 0;
        for (int i = 0; i < nb; ++i) { int v = bp[i]; bp[i] = a; a += v; }
    }
    __syncthreads();
    int i = blockIdx.x * blockDim.x + t;
    if (i < n) rowptr[i] = excl[i] + bp[i >> 10];
    else if (i == n) rowptr[n] = N_EDGES;
}

// ===========================================================================
// Fused CSR fill (atomic-free) + layer-0 GEMM, 3:2 interleaved.
// ===========================================================================
__global__ __launch_bounds__(256) void fill_gemm0(
    const int* __restrict__ src, const int* __restrict__ dst,
    const float* __restrict__ w, const int* __restrict__ rowptr,
    const int* __restrict__ eslot, int2* __restrict__ epack,
    const uint* __restrict__ xb,
    const ushort* __restrict__ whi, const ushort* __restrict__ wlo,
    const float* __restrict__ b, ushort* __restrict__ h) {
    int t = threadIdx.x;
    int bm = blockIdx.x % 5;
    if (bm >= 2) {
        int fid = (blockIdx.x / 5) * 3 + (bm - 2);
        int e = fid * 256 + t;
        if (e < N_EDGES) {
            int d = dst[e];
            epack[rowptr[d] + eslot[e]] = make_int2(src[e], __float_as_int(w[e]));
        }
        return;
    }
    int gid = (blockIdx.x / 5) * 2 + bm;

    __shared__ uint4 sx4[1024];          // 16 KB
    char* sxb = (char*)sx4;
    int lane = t & 63, wv = t >> 6;
    int l15 = lane & 15, l4 = lane >> 4;
    int row0 = gid * 64;
    int c0 = wv * 32;

    bf16x8 Ah[2][4], Al[2][4];
    #pragma unroll
    for (int m = 0; m < 2; ++m) {
        int c = c0 + m * 16 + l15;
        #pragma unroll
        for (int s = 0; s < 4; ++s) {
            int off = c * HIDDEN + s * 32 + l4 * 8;
            Ah[m][s] = *(const bf16x8*)(whi + off);
            Al[m][s] = *(const bf16x8*)(wlo + off);
        }
    }

    #pragma unroll
    for (int j = 0; j < 4; ++j) {
        int c = j * 256 + t;
        int row = c >> 4;
        int colb = (c & 15) * 16;
        int grow = row0 + row;
        if (grow >= N_NODES) grow = N_NODES - 1;
        uint4 v = *(const uint4*)((const char*)xb + (size_t)grow * 256 + colb);
        *(uint4*)(sxb + row * 256 + (colb ^ ((row & 7) << 4))) = v;
    }
    __syncthreads();

    f32x4 acc[2][4];
    #pragma unroll
    for (int m = 0; m < 2; ++m)
        #pragma unroll
        for (int n = 0; n < 4; ++n)
            acc[m][n] = f32x4{0.f, 0.f, 0.f, 0.f};

    #pragma unroll
    for (int n = 0; n < 4; ++n) {
        int row = n * 16 + l15;
        int rsw = (row & 7) << 4;
        #pragma unroll
        for (int s = 0; s < 4; ++s) {
            bf16x8 bh = *(const bf16x8*)(sxb + row * 256 + ((s * 64 + l4 * 16) ^ rsw));
            #pragma unroll
            for (int m = 0; m < 2; ++m) {
                acc[m][n] = __builtin_amdgcn_mfma_f32_16x16x32_bf16(Ah[m][s], bh, acc[m][n], 0, 0, 0);
                acc[m][n] = __builtin_amdgcn_mfma_f32_16x16x32_bf16(Al[m][s], bh, acc[m][n], 0, 0, 0);
            }
        }
    }

    #pragma unroll
    for (int m = 0; m < 2; ++m) {
        f32x4 bias = *(const f32x4*)(b + c0 + m * 16 + l4 * 4);
        #pragma unroll
        for (int n = 0; n < 4; ++n) {
            int node = row0 + n * 16 + l15;
            f32x4 r = acc[m][n] + bias;
            uint2 packed;
            packed.x = (uint)f2bf(r[0]) | ((uint)f2bf(r[1]) << 16);
            packed.y = (uint)f2bf(r[2]) | ((uint)f2bf(r[3]) << 16);
            *(uint2*)(h + (size_t)node * HIDDEN + c0 + m * 16 + l4 * 4) = packed;
        }
    }
}

// ===========================================================================
// Fused agg_i + gemm_{i+1}: EXACT round-14 structure (best measured: 52.4us)
// -- 512 thr / 8 waves, 64-node tiles, 32 groups x 2 passes, non-persistent
// (R15 persistence, R16 small tiles, R17 dual-node all regressed) -- with
// only the gather ladder upgraded to 6/4/2/1.
// ===========================================================================
__global__ __launch_bounds__(512) void agg_gemm(
    const ushort* __restrict__ hprev, const int* __restrict__ rowptr,
    const int2* __restrict__ epack,
    const float* __restrict__ We_l, const float* __restrict__ be_l,
    const float* __restrict__ temp_l, float* __restrict__ energy,
    const ushort* __restrict__ whi, const ushort* __restrict__ wlo,
    const float* __restrict__ b, ushort* __restrict__ hnext) {
    __shared__ uint4 sx4[1024];          // 16 KB
    char* sxb = (char*)sx4;
    int t = threadIdx.x;
    int row0 = blockIdx.x * 64;
    int g = t >> 4, l16 = t & 15;        // 32 groups of 16 lanes
    int cb = l16 * 16;
    const char* hrow = (const char*)hprev;

    // ---- phase A: aggregate 64 nodes (32 groups x 2 passes) ----
    #pragma unroll 1
    for (int p = 0; p < 2; ++p) {
        int r = p * 32 + g;              // tile row 0..63
        int n = row0 + r;
        float a[8] = {0.f, 0.f, 0.f, 0.f, 0.f, 0.f, 0.f, 0.f};
        if (n < N_NODES) {
            int j0 = rowptr[n], j1 = rowptr[n + 1];
            gather_agg(hrow, epack, j0, j1, cb, a);
            #pragma unroll
            for (int q = 0; q < 8; ++q) a[q] = a[q] > 0.f ? a[q] : 0.01f * a[q];
            const float* wer = We_l + l16 * 8;
            float4 we0 = *(const float4*)(wer + 0);
            float4 we1 = *(const float4*)(wer + 4);
            float dot = a[0] * we0.x + a[1] * we0.y + a[2] * we0.z + a[3] * we0.w
                      + a[4] * we1.x + a[5] * we1.y + a[6] * we1.z + a[7] * we1.w;
            #pragma unroll
            for (int off = 8; off > 0; off >>= 1) dot += __shfl_xor(dot, off);
            if (l16 == 0) energy[n] += (dot + be_l[0]) * temp_l[0];
        }
        uint4 packed;
        packed.x = (uint)f2bf(a[0]) | ((uint)f2bf(a[1]) << 16);
        packed.y = (uint)f2bf(a[2]) | ((uint)f2bf(a[3]) << 16);
        packed.z = (uint)f2bf(a[4]) | ((uint)f2bf(a[5]) << 16);
        packed.w = (uint)f2bf(a[6]) | ((uint)f2bf(a[7]) << 16);
        *(uint4*)(sxb + r * 256 + (cb ^ ((r & 7) << 4))) = packed;
    }

    // ---- phase B: gemm from LDS; wave wv owns cols [wv*16, wv*16+16) ----
    int lane = t & 63, wv = t >> 6;
    int l15 = lane & 15, l4 = lane >> 4;
    int c0 = wv * 16;
    bf16x8 Ah[4], Al[4];
    #pragma unroll
    for (int s = 0; s < 4; ++s) {
        int off = (c0 + l15) * HIDDEN + s * 32 + l4 * 8;
        Ah[s] = *(const bf16x8*)(whi + off);
        Al[s] = *(const bf16x8*)(wlo + off);
    }
    __syncthreads();

    f32x4 acc[4];
    #pragma unroll
    for (int n = 0; n < 4; ++n) acc[n] = f32x4{0.f, 0.f, 0.f, 0.f};

    #pragma unroll
    for (int n = 0; n < 4; ++n) {
        int row = n * 16 + l15;
        int rsw = (row & 7) << 4;
        #pragma unroll
        for (int s = 0; s < 4; ++s) {
            bf16x8 bh = *(const bf16x8*)(sxb + row * 256 + ((s * 64 + l4 * 16) ^ rsw));
            acc[n] = __builtin_amdgcn_mfma_f32_16x16x32_bf16(Ah[s], bh, acc[n], 0, 0, 0);
            acc[n] = __builtin_amdgcn_mfma_f32_16x16x32_bf16(Al[s], bh, acc[n], 0, 0, 0);
        }
    }

    float4 bias = *(const float4*)(b + c0 + l4 * 4);
    #pragma unroll
    for (int n = 0; n < 4; ++n) {
        int node = row0 + n * 16 + l15;
        f32x4 r = acc[n];
        r[0] += bias.x; r[1] += bias.y; r[2] += bias.z; r[3] += bias.w;
        uint2 packed;
        packed.x = (uint)f2bf(r[0]) | ((uint)f2bf(r[1]) << 16);
        packed.y = (uint)f2bf(r[2]) | ((uint)f2bf(r[3]) << 16);
        *(uint2*)(hnext + (size_t)node * HIDDEN + c0 + l4 * 4) = packed;
    }
}

// ===========================================================================
// Final aggregation: relu + tap4 + f32 x out.
// ===========================================================================
__global__ void agg_final(const ushort* __restrict__ h, const int* __restrict__ rowptr,
                          const int2* __restrict__ epack,
                          const float* __restrict__ We_l, const float* __restrict__ be_l,
                          const float* __restrict__ temp_l,
                          float* __restrict__ xout, float* __restrict__ energy) {
    int gtid = blockIdx.x * blockDim.x + threadIdx.x;
    int n = gtid >> 4;
    int l16 = gtid & 15;
    if (n >= N_NODES) return;
    int j0 = rowptr[n], j1 = rowptr[n + 1];
    int cb = l16 * 16;
    float a[8] = {0.f, 0.f, 0.f, 0.f, 0.f, 0.f, 0.f, 0.f};
    gather_agg((const char*)h, epack, j0, j1, cb, a);
    #pragma unroll
    for (int q = 0; q < 8; ++q) a[q] = a[q] > 0.f ? a[q] : 0.01f * a[q];

    float* orow = xout + (size_t)n * HIDDEN + l16 * 8;
    *(float4*)(orow + 0) = float4{a[0], a[1], a[2], a[3]};
    *(float4*)(orow + 4) = float4{a[4], a[5], a[6], a[7]};

    const float* wer = We_l + l16 * 8;
    float4 we0 = *(const float4*)(wer + 0);
    float4 we1 = *(const float4*)(wer + 4);
    float dot = a[0] * we0.x + a[1] * we0.y + a[2] * we0.z + a[3] * we0.w
              + a[4] * we1.x + a[5] * we1.y + a[6] * we1.z + a[7] * we1.w;
    #pragma unroll
    for (int off = 8; off > 0; off >>= 1) dot += __shfl_xor(dot, off);
    if (l16 == 0) energy[n] += (dot + be_l[0]) * temp_l[0];
}

extern "C" void kernel_launch(void* const* d_in, const int* in_sizes, int n_in,
                              void* d_out, int out_size, void* d_ws, size_t ws_size,
                              hipStream_t stream) {
    const float* x    = (const float*)d_in[0];
    const int*   src  = (const int*)d_in[1];
    const int*   dst  = (const int*)d_in[2];
    const float* w    = (const float*)d_in[3];
    const float* Ws   = (const float*)d_in[4];
    const float* bs   = (const float*)d_in[5];
    const float* We   = (const float*)d_in[6];
    const float* be   = (const float*)d_in[7];
    const float* temp = (const float*)d_in[8];

    float* energy = (float*)d_out;            // [N]
    float* xout   = (float*)d_out + N_NODES;  // [N,128] f32 final x
    uint* xb = (uint*)xout;                   // bf16 x0 scratch aliases xout

    // workspace
    ushort* h0     = (ushort*)d_ws;                       // MPAD*128 bf16
    ushort* h1     = h0 + (size_t)MPAD * HIDDEN;          // MPAD*128 bf16
    int2*   epack  = (int2*)(h1 + (size_t)MPAD * HIDDEN); // E (8B each)
    int*    cnt    = (int*)(epack + N_EDGES);             // N*CPAD (padded)
    int*    eslot  = cnt + (size_t)N_NODES * CPAD;        // E
    int*    excl   = eslot + N_EDGES;
    int*    bsums  = excl + N_NODES;                      // 128
    int*    rowptr = bsums + 128;                         // N+1
    ushort* whi    = (ushort*)(rowptr + N_NODES + 4);     // 4*128*128
    ushort* wlo    = whi + N_LAYERS * HIDDEN * HIDDEN;

    // ---- zero padded cnt (6.4MB) ----
    hipMemsetAsync(cnt, 0, (size_t)N_NODES * CPAD * sizeof(int), stream);

    // ---- fused prologue: tap0+cast | count_dst(+eslot) | prep_w ----
    prologue<<<TAP0_BLOCKS + CNT_BLOCKS + PREPW_BLOCKS, 256, 0, stream>>>(
        x, We, be, temp, energy, xb, dst, cnt, eslot, Ws, whi, wlo);

    // ---- scan -> rowptr ----
    int nblk = (N_NODES + 1023) / 1024;   // 98
    scan1<<<nblk, 256, 0, stream>>>(cnt, excl, bsums, N_NODES);
    scan23<<<(N_NODES + 1 + 255) / 256, 256, 0, stream>>>(excl, bsums, rowptr, N_NODES, nblk);

    // ---- fused CSR fill (atomic-free) + gemm0 (3:2 interleaved) ----
    fill_gemm0<<<GEMM_BLOCKS + CNT_BLOCKS, 256, 0, stream>>>(
        src, dst, w, rowptr, eslot, epack, xb, whi, wlo, bs, h0);

    // ---- fused agg_i + gemm_{i+1} (R14 structure, 6-wide ladder), ping-pong ----
    agg_gemm<<<GEMM_BLOCKS, 512, 0, stream>>>(
        h0, rowptr, epack, We + 1 * HIDDEN, be + 1, temp + 1, energy,
        whi + 1 * HIDDEN * HIDDEN, wlo + 1 * HIDDEN * HIDDEN, bs + 1 * HIDDEN, h1);
    agg_gemm<<<GEMM_BLOCKS, 512, 0, stream>>>(
        h1, rowptr, epack, We + 2 * HIDDEN, be + 2, temp + 2, energy,
        whi + 2 * HIDDEN * HIDDEN, wlo + 2 * HIDDEN * HIDDEN, bs + 2 * HIDDEN, h0);
    agg_gemm<<<GEMM_BLOCKS, 512, 0, stream>>>(
        h0, rowptr, epack, We + 3 * HIDDEN, be + 3, temp + 3, energy,
        whi + 3 * HIDDEN * HIDDEN, wlo + 3 * HIDDEN * HIDDEN, bs + 3 * HIDDEN, h1);

    // ---- final agg: relu + tap4 + f32 x ----
    agg_final<<<(N_NODES * 16 + 255) / 256, 256, 0, stream>>>(
        h1, rowptr, epack, We + 4 * HIDDEN, be + 4, temp + 4, xout, energy);
}

// Round 19
// 265.931 us; speedup vs baseline: 1.0747x; 1.0747x over previous
//
#include <hip/hip_runtime.h>
#include <hip/hip_bf16.h>

#define N_NODES 100000
#define N_EDGES 600000
#define HIDDEN 128
#define N_LAYERS 4
#define MPAD 100096   // N_NODES rounded up to 128 (and to 64)
#define CPAD 16       // counter padding: one counter per 64B line

#define TAP0_BLOCKS ((N_NODES * 16) / 256)                       // 6250
#define CNT_BLOCKS ((N_EDGES + 255) / 256)                       // 2344
#define PREPW_BLOCKS ((N_LAYERS * HIDDEN * HIDDEN + 255) / 256)  // 256
#define GEMM_BLOCKS (MPAD / 64)                                  // 1564

typedef short bf16x8 __attribute__((ext_vector_type(8)));
typedef float f32x4 __attribute__((ext_vector_type(4)));
typedef float f32x8 __attribute__((ext_vector_type(8)));

__device__ inline ushort f2bf(float f) {
    __hip_bfloat16 h = __float2bfloat16(f);
    return *reinterpret_cast<ushort*>(&h);
}

__device__ inline float bfhi(uint u) { return __uint_as_float(u << 16); }
__device__ inline float bflo(uint u) { return __uint_as_float(u & 0xffff0000u); }

// Gather body (round-8/14 proven optimum): 16 lanes/node, uint4/lane,
// exact-width 4/2/1 rounds, ONE shared loop body.
// Five structural variants (R9 tiers, R15 persistence, R16 small tiles,
// R17 dual-node, R18 6-wide) ALL regressed vs this form - do not touch.
#define FMA8(U, P) { float wk = __int_as_float(P.y); \
    a[0] += bfhi(U.x) * wk; a[1] += bflo(U.x) * wk; \
    a[2] += bfhi(U.y) * wk; a[3] += bflo(U.y) * wk; \
    a[4] += bfhi(U.z) * wk; a[5] += bflo(U.z) * wk; \
    a[6] += bfhi(U.w) * wk; a[7] += bflo(U.w) * wk; }

__device__ __forceinline__ void gather_agg(const char* __restrict__ hrow,
                                           const int2* __restrict__ epack,
                                           int j0, int j1, int cb, float* a) {
    int j = j0;
    for (; j + 4 <= j1; j += 4) {
        int2 p0 = epack[j], p1 = epack[j + 1], p2 = epack[j + 2], p3 = epack[j + 3];
        uint4 u0 = *(const uint4*)(hrow + (size_t)p0.x * 256 + cb);
        uint4 u1 = *(const uint4*)(hrow + (size_t)p1.x * 256 + cb);
        uint4 u2 = *(const uint4*)(hrow + (size_t)p2.x * 256 + cb);
        uint4 u3 = *(const uint4*)(hrow + (size_t)p3.x * 256 + cb);
        FMA8(u0, p0); FMA8(u1, p1); FMA8(u2, p2); FMA8(u3, p3);
    }
    if (j + 2 <= j1) {
        int2 p0 = epack[j], p1 = epack[j + 1];
        uint4 u0 = *(const uint4*)(hrow + (size_t)p0.x * 256 + cb);
        uint4 u1 = *(const uint4*)(hrow + (size_t)p1.x * 256 + cb);
        FMA8(u0, p0); FMA8(u1, p1);
        j += 2;
    }
    if (j < j1) {
        int2 p0 = epack[j];
        uint4 u0 = *(const uint4*)(hrow + (size_t)p0.x * 256 + cb);
        FMA8(u0, p0);
    }
}

// ===========================================================================
// Prologue (fused independent prep): tap0+cast x0 | count_dst(+eslot) | prep_w
// ===========================================================================
__global__ void prologue(const float* __restrict__ x, const float* __restrict__ We,
                         const float* __restrict__ be, const float* __restrict__ temp,
                         float* __restrict__ energy, uint* __restrict__ xb,
                         const int* __restrict__ dst, int* __restrict__ cnt,
                         int* __restrict__ eslot,
                         const float* __restrict__ Ws, ushort* __restrict__ whi,
                         ushort* __restrict__ wlo) {
    int b = blockIdx.x;
    if (b < TAP0_BLOCKS) {
        int gtid = b * 256 + threadIdx.x;
        int n = gtid >> 4, l16 = gtid & 15;
        f32x8 v = *(const f32x8*)(x + (size_t)n * HIDDEN + l16 * 8);
        uint4 packed;
        packed.x = (uint)f2bf(v[0]) | ((uint)f2bf(v[1]) << 16);
        packed.y = (uint)f2bf(v[2]) | ((uint)f2bf(v[3]) << 16);
        packed.z = (uint)f2bf(v[4]) | ((uint)f2bf(v[5]) << 16);
        packed.w = (uint)f2bf(v[6]) | ((uint)f2bf(v[7]) << 16);
        ((uint4*)(xb + (size_t)n * 64))[l16] = packed;
        f32x8 we = *(const f32x8*)(We + l16 * 8);
        float dot = v[0] * we[0] + v[1] * we[1] + v[2] * we[2] + v[3] * we[3]
                  + v[4] * we[4] + v[5] * we[5] + v[6] * we[6] + v[7] * we[7];
        #pragma unroll
        for (int off = 8; off > 0; off >>= 1) dot += __shfl_xor(dot, off);
        if (l16 == 0) energy[n] = (dot + be[0]) * temp[0];
    } else if (b < TAP0_BLOCKS + CNT_BLOCKS) {
        int e = (b - TAP0_BLOCKS) * 256 + threadIdx.x;
        if (e < N_EDGES)
            eslot[e] = atomicAdd(&cnt[(size_t)dst[e] * CPAD], 1);
    } else {
        int idx = (b - TAP0_BLOCKS - CNT_BLOCKS) * 256 + threadIdx.x;
        if (idx < N_LAYERS * HIDDEN * HIDDEN) {
            int l = idx >> 14;
            int r = idx & 16383;
            int c = r >> 7, k = r & 127;
            float v = Ws[(l << 14) + k * HIDDEN + c];
            ushort hi = f2bf(v);
            float hif = __uint_as_float(((uint)hi) << 16);
            whi[idx] = hi;
            wlo[idx] = f2bf(v - hif);
        }
    }
}

// ===========================================================================
// Exclusive scan over padded cnt -> rowptr (scan1 + merged scan23)
// ===========================================================================
__global__ void scan1(const int* __restrict__ cnt, int* __restrict__ excl,
                      int* __restrict__ bsums, int n) {
    __shared__ int lds[8];
    int t = threadIdx.x;
    int base = blockIdx.x * 1024 + t * 4;
    int v0 = (base + 0 < n) ? cnt[(size_t)(base + 0) * CPAD] : 0;
    int v1 = (base + 1 < n) ? cnt[(size_t)(base + 1) * CPAD] : 0;
    int v2 = (base + 2 < n) ? cnt[(size_t)(base + 2) * CPAD] : 0;
    int v3 = (base + 3 < n) ? cnt[(size_t)(base + 3) * CPAD] : 0;
    int tsum = v0 + v1 + v2 + v3;
    int lane = t & 63, wv = t >> 6;
    int s = tsum;
    #pragma unroll
    for (int off = 1; off < 64; off <<= 1) {
        int u = __shfl_up(s, off);
        if (lane >= off) s += u;
    }
    if (lane == 63) lds[wv] = s;
    __syncthreads();
    if (t == 0) {
        int a = 0;
        #pragma unroll
        for (int i = 0; i < 4; ++i) { int bb = lds[i]; lds[i] = a; a += bb; }
        lds[4] = a;
    }
    __syncthreads();
    int excl_t = (s - tsum) + lds[wv];
    if (base + 0 < n) excl[base + 0] = excl_t;
    if (base + 1 < n) excl[base + 1] = excl_t + v0;
    if (base + 2 < n) excl[base + 2] = excl_t + v0 + v1;
    if (base + 3 < n) excl[base + 3] = excl_t + v0 + v1 + v2;
    if (t == 0) bsums[blockIdx.x] = lds[4];
}

__global__ void scan23(const int* __restrict__ excl, const int* __restrict__ bsums,
                       int* __restrict__ rowptr, int n, int nb) {
    __shared__ int bp[128];
    int t = threadIdx.x;
    if (t < nb) bp[t] = bsums[t];
    __syncthreads();
    if (t == 0) {
        int a = 0;
        for (int i = 0; i < nb; ++i) { int v = bp[i]; bp[i] = a; a += v; }
    }
    __syncthreads();
    int i = blockIdx.x * blockDim.x + t;
    if (i < n) rowptr[i] = excl[i] + bp[i >> 10];
    else if (i == n) rowptr[n] = N_EDGES;
}

// ===========================================================================
// Fused CSR fill (atomic-free) + layer-0 GEMM, 3:2 interleaved.
// ===========================================================================
__global__ __launch_bounds__(256) void fill_gemm0(
    const int* __restrict__ src, const int* __restrict__ dst,
    const float* __restrict__ w, const int* __restrict__ rowptr,
    const int* __restrict__ eslot, int2* __restrict__ epack,
    const uint* __restrict__ xb,
    const ushort* __restrict__ whi, const ushort* __restrict__ wlo,
    const float* __restrict__ b, ushort* __restrict__ h) {
    int t = threadIdx.x;
    int bm = blockIdx.x % 5;
    if (bm >= 2) {
        int fid = (blockIdx.x / 5) * 3 + (bm - 2);
        int e = fid * 256 + t;
        if (e < N_EDGES) {
            int d = dst[e];
            epack[rowptr[d] + eslot[e]] = make_int2(src[e], __float_as_int(w[e]));
        }
        return;
    }
    int gid = (blockIdx.x / 5) * 2 + bm;

    __shared__ uint4 sx4[1024];          // 16 KB
    char* sxb = (char*)sx4;
    int lane = t & 63, wv = t >> 6;
    int l15 = lane & 15, l4 = lane >> 4;
    int row0 = gid * 64;
    int c0 = wv * 32;

    bf16x8 Ah[2][4], Al[2][4];
    #pragma unroll
    for (int m = 0; m < 2; ++m) {
        int c = c0 + m * 16 + l15;
        #pragma unroll
        for (int s = 0; s < 4; ++s) {
            int off = c * HIDDEN + s * 32 + l4 * 8;
            Ah[m][s] = *(const bf16x8*)(whi + off);
            Al[m][s] = *(const bf16x8*)(wlo + off);
        }
    }

    #pragma unroll
    for (int j = 0; j < 4; ++j) {
        int c = j * 256 + t;
        int row = c >> 4;
        int colb = (c & 15) * 16;
        int grow = row0 + row;
        if (grow >= N_NODES) grow = N_NODES - 1;
        uint4 v = *(const uint4*)((const char*)xb + (size_t)grow * 256 + colb);
        *(uint4*)(sxb + row * 256 + (colb ^ ((row & 7) << 4))) = v;
    }
    __syncthreads();

    f32x4 acc[2][4];
    #pragma unroll
    for (int m = 0; m < 2; ++m)
        #pragma unroll
        for (int n = 0; n < 4; ++n)
            acc[m][n] = f32x4{0.f, 0.f, 0.f, 0.f};

    #pragma unroll
    for (int n = 0; n < 4; ++n) {
        int row = n * 16 + l15;
        int rsw = (row & 7) << 4;
        #pragma unroll
        for (int s = 0; s < 4; ++s) {
            bf16x8 bh = *(const bf16x8*)(sxb + row * 256 + ((s * 64 + l4 * 16) ^ rsw));
            #pragma unroll
            for (int m = 0; m < 2; ++m) {
                acc[m][n] = __builtin_amdgcn_mfma_f32_16x16x32_bf16(Ah[m][s], bh, acc[m][n], 0, 0, 0);
                acc[m][n] = __builtin_amdgcn_mfma_f32_16x16x32_bf16(Al[m][s], bh, acc[m][n], 0, 0, 0);
            }
        }
    }

    #pragma unroll
    for (int m = 0; m < 2; ++m) {
        f32x4 bias = *(const f32x4*)(b + c0 + m * 16 + l4 * 4);
        #pragma unroll
        for (int n = 0; n < 4; ++n) {
            int node = row0 + n * 16 + l15;
            f32x4 r = acc[m][n] + bias;
            uint2 packed;
            packed.x = (uint)f2bf(r[0]) | ((uint)f2bf(r[1]) << 16);
            packed.y = (uint)f2bf(r[2]) | ((uint)f2bf(r[3]) << 16);
            *(uint2*)(h + (size_t)node * HIDDEN + c0 + m * 16 + l4 * 4) = packed;
        }
    }
}

// ===========================================================================
// Fused agg_i + gemm_{i+1}: round-14 structure, best measured (52.4us/layer).
// 512 thr / 8 waves, 64-node tiles, 32 groups x 2 passes, non-persistent.
// ===========================================================================
__global__ __launch_bounds__(512) void agg_gemm(
    const ushort* __restrict__ hprev, const int* __restrict__ rowptr,
    const int2* __restrict__ epack,
    const float* __restrict__ We_l, const float* __restrict__ be_l,
    const float* __restrict__ temp_l, float* __restrict__ energy,
    const ushort* __restrict__ whi, const ushort* __restrict__ wlo,
    const float* __restrict__ b, ushort* __restrict__ hnext) {
    __shared__ uint4 sx4[1024];          // 16 KB
    char* sxb = (char*)sx4;
    int t = threadIdx.x;
    int row0 = blockIdx.x * 64;
    int g = t >> 4, l16 = t & 15;        // 32 groups of 16 lanes
    int cb = l16 * 16;
    const char* hrow = (const char*)hprev;

    // ---- phase A: aggregate 64 nodes (32 groups x 2 passes) ----
    #pragma unroll 1
    for (int p = 0; p < 2; ++p) {
        int r = p * 32 + g;              // tile row 0..63
        int n = row0 + r;
        float a[8] = {0.f, 0.f, 0.f, 0.f, 0.f, 0.f, 0.f, 0.f};
        if (n < N_NODES) {
            int j0 = rowptr[n], j1 = rowptr[n + 1];
            gather_agg(hrow, epack, j0, j1, cb, a);
            #pragma unroll
            for (int q = 0; q < 8; ++q) a[q] = a[q] > 0.f ? a[q] : 0.01f * a[q];
            const float* wer = We_l + l16 * 8;
            float4 we0 = *(const float4*)(wer + 0);
            float4 we1 = *(const float4*)(wer + 4);
            float dot = a[0] * we0.x + a[1] * we0.y + a[2] * we0.z + a[3] * we0.w
                      + a[4] * we1.x + a[5] * we1.y + a[6] * we1.z + a[7] * we1.w;
            #pragma unroll
            for (int off = 8; off > 0; off >>= 1) dot += __shfl_xor(dot, off);
            if (l16 == 0) energy[n] += (dot + be_l[0]) * temp_l[0];
        }
        uint4 packed;
        packed.x = (uint)f2bf(a[0]) | ((uint)f2bf(a[1]) << 16);
        packed.y = (uint)f2bf(a[2]) | ((uint)f2bf(a[3]) << 16);
        packed.z = (uint)f2bf(a[4]) | ((uint)f2bf(a[5]) << 16);
        packed.w = (uint)f2bf(a[6]) | ((uint)f2bf(a[7]) << 16);
        *(uint4*)(sxb + r * 256 + (cb ^ ((r & 7) << 4))) = packed;
    }

    // ---- phase B: gemm from LDS; wave wv owns cols [wv*16, wv*16+16) ----
    int lane = t & 63, wv = t >> 6;
    int l15 = lane & 15, l4 = lane >> 4;
    int c0 = wv * 16;
    bf16x8 Ah[4], Al[4];
    #pragma unroll
    for (int s = 0; s < 4; ++s) {
        int off = (c0 + l15) * HIDDEN + s * 32 + l4 * 8;
        Ah[s] = *(const bf16x8*)(whi + off);
        Al[s] = *(const bf16x8*)(wlo + off);
    }
    __syncthreads();

    f32x4 acc[4];
    #pragma unroll
    for (int n = 0; n < 4; ++n) acc[n] = f32x4{0.f, 0.f, 0.f, 0.f};

    #pragma unroll
    for (int n = 0; n < 4; ++n) {
        int row = n * 16 + l15;
        int rsw = (row & 7) << 4;
        #pragma unroll
        for (int s = 0; s < 4; ++s) {
            bf16x8 bh = *(const bf16x8*)(sxb + row * 256 + ((s * 64 + l4 * 16) ^ rsw));
            acc[n] = __builtin_amdgcn_mfma_f32_16x16x32_bf16(Ah[s], bh, acc[n], 0, 0, 0);
            acc[n] = __builtin_amdgcn_mfma_f32_16x16x32_bf16(Al[s], bh, acc[n], 0, 0, 0);
        }
    }

    float4 bias = *(const float4*)(b + c0 + l4 * 4);
    #pragma unroll
    for (int n = 0; n < 4; ++n) {
        int node = row0 + n * 16 + l15;
        f32x4 r = acc[n];
        r[0] += bias.x; r[1] += bias.y; r[2] += bias.z; r[3] += bias.w;
        uint2 packed;
        packed.x = (uint)f2bf(r[0]) | ((uint)f2bf(r[1]) << 16);
        packed.y = (uint)f2bf(r[2]) | ((uint)f2bf(r[3]) << 16);
        *(uint2*)(hnext + (size_t)node * HIDDEN + c0 + l4 * 4) = packed;
    }
}

// ===========================================================================
// Final aggregation: relu + tap4 + f32 x out.
// ===========================================================================
__global__ void agg_final(const ushort* __restrict__ h, const int* __restrict__ rowptr,
                          const int2* __restrict__ epack,
                          const float* __restrict__ We_l, const float* __restrict__ be_l,
                          const float* __restrict__ temp_l,
                          float* __restrict__ xout, float* __restrict__ energy) {
    int gtid = blockIdx.x * blockDim.x + threadIdx.x;
    int n = gtid >> 4;
    int l16 = gtid & 15;
    if (n >= N_NODES) return;
    int j0 = rowptr[n], j1 = rowptr[n + 1];
    int cb = l16 * 16;
    float a[8] = {0.f, 0.f, 0.f, 0.f, 0.f, 0.f, 0.f, 0.f};
    gather_agg((const char*)h, epack, j0, j1, cb, a);
    #pragma unroll
    for (int q = 0; q < 8; ++q) a[q] = a[q] > 0.f ? a[q] : 0.01f * a[q];

    float* orow = xout + (size_t)n * HIDDEN + l16 * 8;
    *(float4*)(orow + 0) = float4{a[0], a[1], a[2], a[3]};
    *(float4*)(orow + 4) = float4{a[4], a[5], a[6], a[7]};

    const float* wer = We_l + l16 * 8;
    float4 we0 = *(const float4*)(wer + 0);
    float4 we1 = *(const float4*)(wer + 4);
    float dot = a[0] * we0.x + a[1] * we0.y + a[2] * we0.z + a[3] * we0.w
              + a[4] * we1.x + a[5] * we1.y + a[6] * we1.z + a[7] * we1.w;
    #pragma unroll
    for (int off = 8; off > 0; off >>= 1) dot += __shfl_xor(dot, off);
    if (l16 == 0) energy[n] += (dot + be_l[0]) * temp_l[0];
}

extern "C" void kernel_launch(void* const* d_in, const int* in_sizes, int n_in,
                              void* d_out, int out_size, void* d_ws, size_t ws_size,
                              hipStream_t stream) {
    const float* x    = (const float*)d_in[0];
    const int*   src  = (const int*)d_in[1];
    const int*   dst  = (const int*)d_in[2];
    const float* w    = (const float*)d_in[3];
    const float* Ws   = (const float*)d_in[4];
    const float* bs   = (const float*)d_in[5];
    const float* We   = (const float*)d_in[6];
    const float* be   = (const float*)d_in[7];
    const float* temp = (const float*)d_in[8];

    float* energy = (float*)d_out;            // [N]
    float* xout   = (float*)d_out + N_NODES;  // [N,128] f32 final x
    uint* xb = (uint*)xout;                   // bf16 x0 scratch aliases xout

    // workspace
    ushort* h0     = (ushort*)d_ws;                       // MPAD*128 bf16
    ushort* h1     = h0 + (size_t)MPAD * HIDDEN;          // MPAD*128 bf16
    int2*   epack  = (int2*)(h1 + (size_t)MPAD * HIDDEN); // E (8B each)
    int*    cnt    = (int*)(epack + N_EDGES);             // N*CPAD (padded)
    int*    eslot  = cnt + (size_t)N_NODES * CPAD;        // E
    int*    excl   = eslot + N_EDGES;
    int*    bsums  = excl + N_NODES;                      // 128
    int*    rowptr = bsums + 128;                         // N+1
    ushort* whi    = (ushort*)(rowptr + N_NODES + 4);     // 4*128*128
    ushort* wlo    = whi + N_LAYERS * HIDDEN * HIDDEN;

    // ---- zero padded cnt (6.4MB) ----
    hipMemsetAsync(cnt, 0, (size_t)N_NODES * CPAD * sizeof(int), stream);

    // ---- fused prologue: tap0+cast | count_dst(+eslot) | prep_w ----
    prologue<<<TAP0_BLOCKS + CNT_BLOCKS + PREPW_BLOCKS, 256, 0, stream>>>(
        x, We, be, temp, energy, xb, dst, cnt, eslot, Ws, whi, wlo);

    // ---- scan -> rowptr ----
    int nblk = (N_NODES + 1023) / 1024;   // 98
    scan1<<<nblk, 256, 0, stream>>>(cnt, excl, bsums, N_NODES);
    scan23<<<(N_NODES + 1 + 255) / 256, 256, 0, stream>>>(excl, bsums, rowptr, N_NODES, nblk);

    // ---- fused CSR fill (atomic-free) + gemm0 (3:2 interleaved) ----
    fill_gemm0<<<GEMM_BLOCKS + CNT_BLOCKS, 256, 0, stream>>>(
        src, dst, w, rowptr, eslot, epack, xb, whi, wlo, bs, h0);

    // ---- fused agg_i + gemm_{i+1} (512 thr), h ping-pong ----
    agg_gemm<<<GEMM_BLOCKS, 512, 0, stream>>>(
        h0, rowptr, epack, We + 1 * HIDDEN, be + 1, temp + 1, energy,
        whi + 1 * HIDDEN * HIDDEN, wlo + 1 * HIDDEN * HIDDEN, bs + 1 * HIDDEN, h1);
    agg_gemm<<<GEMM_BLOCKS, 512, 0, stream>>>(
        h1, rowptr, epack, We + 2 * HIDDEN, be + 2, temp + 2, energy,
        whi + 2 * HIDDEN * HIDDEN, wlo + 2 * HIDDEN * HIDDEN, bs + 2 * HIDDEN, h0);
    agg_gemm<<<GEMM_BLOCKS, 512, 0, stream>>>(
        h0, rowptr, epack, We + 3 * HIDDEN, be + 3, temp + 3, energy,
        whi + 3 * HIDDEN * HIDDEN, wlo + 3 * HIDDEN * HIDDEN, bs + 3 * HIDDEN, h1);

    // ---- final agg: relu + tap4 + f32 x ----
    agg_final<<<(N_NODES * 16 + 255) / 256, 256, 0, stream>>>(
        h1, rowptr, epack, We + 4 * HIDDEN, be + 4, temp + 4, xout, energy);
}